// Round 22
// baseline (227.569 us; speedup 1.0000x reference)
//
#include <hip/hip_runtime.h>
#include <math.h>

#define EPS_ 1e-10f
#define MARGIN 4e-3f

typedef __attribute__((ext_vector_type(8))) short sh8;
typedef __attribute__((ext_vector_type(4))) float fx4;

__device__ __forceinline__ bool betterf(float v, int i, float w, int j) {
    return (v > w) || (v == w && i < j);
}
__device__ __forceinline__ bool betterd(double v, int i, double w, int j) {
    return (v > w) || (v == w && i < j);
}
__device__ __forceinline__ unsigned short f2bf(float f) {   // RNE
    unsigned u = __float_as_uint(f);
    u += 0x7fffu + ((u >> 16) & 1u);
    return (unsigned short)(u >> 16);
}
__device__ __forceinline__ float bf2f(unsigned short h) {
    return __uint_as_float(((unsigned)h) << 16);
}
__device__ __forceinline__ void cvt8(const float4 a, const float4 c, sh8& hi, sh8& lo) {
    const float v[8] = {a.x, a.y, a.z, a.w, c.x, c.y, c.z, c.w};
#pragma unroll
    for (int j = 0; j < 8; ++j) {
        const unsigned short h = f2bf(v[j]);
        hi[j] = (short)h;
        lo[j] = (short)f2bf(v[j] - bf2f(h));
    }
}
__device__ __forceinline__ void gload_lds16(const void* g, void* l) {
    __builtin_amdgcn_global_load_lds(
        (const __attribute__((address_space(1))) void*)g,
        (__attribute__((address_space(3))) void*)l, 16, 0, 0);
}

// ---------------------------------------------------------------------------
// One-time W conversion into B-fragment layout, bf16 hi/lo (layout verified).
// ---------------------------------------------------------------------------
__global__ __launch_bounds__(256)
void wconv(const float* __restrict__ W, unsigned short* __restrict__ wf)
{
    const int gid = blockIdx.x * 256 + threadIdx.x;   // dim*64
    const int e = gid & 63, k = gid >> 6;
    const int s = k >> 5, kk = k & 31, bq = kk >> 3, j = kk & 7;
    const int t = e >> 4, n = e & 15;
    const int l = n + 16 * bq;
    const float w = W[(size_t)k * 64 + e];
    const unsigned short hi = f2bf(w);
    const unsigned short lo = f2bf(w - bf2f(hi));
    const size_t base = ((size_t)s * 4 + t) * 2;
    wf[(base + 0) * 512 + l * 8 + j] = hi;
    wf[(base + 1) * 512 + l * 8 + j] = lo;
}

// ---------------------------------------------------------------------------
// MFMA GEMM (R18 form: 2 buffers, one __syncthreads per step, 4 blocks/CU)
// + LAST-BLOCK-FUSED epilogue: each block writes its zpart slice, fences
// (device scope), bumps done[rg]; the 4th arrival acquires and runs the
// verified merge+epilogue (top-2/softmax/rz/hist/flags) for its 64 rows.
// Deterministic: merge sums slices in fixed ks order. Removes merge_epi32.
// ---------------------------------------------------------------------------
#define KSPL 4
__global__ __launch_bounds__(256, 4)
void gemm_mfma(const float* __restrict__ x, const unsigned short* __restrict__ wfg,
               const float* __restrict__ b, const int* __restrict__ sl_p,
               int dim, int N, int nchunks, float* __restrict__ zpart,
               float* __restrict__ ts, int* __restrict__ sel,
               int* __restrict__ nflags, int* __restrict__ flaglist,
               int* __restrict__ hist, int* __restrict__ cnt2,
               double* __restrict__ bsum, int* __restrict__ done)
{
    __shared__ __align__(16) char xs[2][8192];    // [buf][64 rows][32 k fp32]
    __shared__ __align__(16) char wls[2][8192];   // [buf][one K=32 W step]
    __shared__ int cnt[2][64];
    __shared__ float rsum[4];
    __shared__ int lastflag;

    const int tid  = threadIdx.x;
    const int lane = tid & 63;
    const int wv   = tid >> 6;
    const int rgs  = N / 64;
    const int ks   = blockIdx.x / rgs;
    const int rg   = blockIdx.x % rgs;
    const int r0   = rg * 64;
    const int kslice = dim / KSPL;            // 512
    const int k0   = ks * kslice;
    const int nstep = kslice / 32;            // 16

    const int m = lane & 15;
    const int q = lane >> 4;
    const int arow = wv * 16 + m;
    const int mk = m & 7;

    const int srow_in = lane >> 3;            // 0..7
    const int sgc     = (lane & 7) ^ (srow_in & 7);

    fx4 acc[4] = {};

    const char* wbytes = (const char*)wfg;
    const size_t wstep0 = (size_t)(k0 >> 5) * 8192;

    // prologue: stage step 0 into buf 0
#pragma unroll
    for (int r = 0; r < 2; ++r) {
        const int row = wv * 16 + r * 8 + srow_in;
        gload_lds16(x + (size_t)(r0 + row) * dim + k0 + sgc * 4,
                    &xs[0][(wv * 16 + r * 8) * 128]);
        gload_lds16(wbytes + wstep0 + wv * 2048 + r * 1024 + lane * 16,
                    &wls[0][wv * 2048 + r * 1024]);
    }
    __syncthreads();

    for (int s = 0; s < nstep; ++s) {
        const int cb = s & 1;
        if (s + 1 < nstep) {
#pragma unroll
            for (int r = 0; r < 2; ++r) {
                const int row = wv * 16 + r * 8 + srow_in;
                gload_lds16(x + (size_t)(r0 + row) * dim + k0 + (s + 1) * 32 + sgc * 4,
                            &xs[cb ^ 1][(wv * 16 + r * 8) * 128]);
                gload_lds16(wbytes + wstep0 + (size_t)(s + 1) * 8192
                                  + wv * 2048 + r * 1024 + lane * 16,
                            &wls[cb ^ 1][wv * 2048 + r * 1024]);
            }
        }
        {
            const float4 f0 = *(const float4*)&xs[cb][arow * 128 + ((2 * q + 0) ^ mk) * 16];
            const float4 f1 = *(const float4*)&xs[cb][arow * 128 + ((2 * q + 1) ^ mk) * 16];
            sh8 ah, al;
            cvt8(f0, f1, ah, al);
#pragma unroll
            for (int te = 0; te < 4; ++te) {
                const sh8 bh = __builtin_bit_cast(sh8,
                    *(const int4*)&wls[cb][(te * 2 + 0) * 1024 + lane * 16]);
                const sh8 bl = __builtin_bit_cast(sh8,
                    *(const int4*)&wls[cb][(te * 2 + 1) * 1024 + lane * 16]);
                acc[te] = __builtin_amdgcn_mfma_f32_16x16x32_bf16(ah, bh, acc[te], 0, 0, 0);
                acc[te] = __builtin_amdgcn_mfma_f32_16x16x32_bf16(ah, bl, acc[te], 0, 0, 0);
                acc[te] = __builtin_amdgcn_mfma_f32_16x16x32_bf16(al, bh, acc[te], 0, 0, 0);
            }
        }
        __syncthreads();
    }

    // store zpart[ks][row][e]
    const int n = lane & 15;
    const int g = lane >> 4;
    float* zp = zpart + ((size_t)ks * N + r0 + wv * 16) * 64;
#pragma unroll
    for (int te = 0; te < 4; ++te)
#pragma unroll
        for (int i = 0; i < 4; ++i)
            zp[(g * 4 + i) * 64 + te * 16 + n] = acc[te][i];

    // ---- last-block-fused merge + epilogue ----
    if (tid < 128) cnt[tid >> 6][tid & 63] = 0;
    __threadfence();                      // release zpart writes (device scope)
    if (tid == 0) {
        const int old = atomicAdd(&done[rg], 1);
        lastflag = (old == KSPL - 1);
    }
    __syncthreads();
    if (!lastflag) return;
    __threadfence();                      // acquire other slices

    const int e = lane;
    const float be = b[e];
    const int lc = wv >> 1;               // local chunk (32 rows each)
    float myrz = 0.0f;

    for (int rr = 0; rr < 16; ++rr) {
        const int row = r0 + wv * 16 + rr;
        float z = be;
#pragma unroll
        for (int s2 = 0; s2 < KSPL; ++s2)
            z += zpart[((size_t)s2 * N + row) * 64 + e];

        float v1 = z, v2 = -3.4e38f;
        int i1 = e, i2 = 1 << 30;
#pragma unroll
        for (int mm = 1; mm < 64; mm <<= 1) {
            const float wva = __shfl_xor(v1, mm, 64); const int j1 = __shfl_xor(i1, mm, 64);
            const float wvb = __shfl_xor(v2, mm, 64); const int j2 = __shfl_xor(i2, mm, 64);
            if (betterf(wva, j1, v1, i1)) {
                float nv2; int ni2;
                if (betterf(v1, i1, wvb, j2)) { nv2 = v1; ni2 = i1; }
                else                          { nv2 = wvb; ni2 = j2; }
                v1 = wva; i1 = j1; v2 = nv2; i2 = ni2;
            } else if (betterf(wva, j1, v2, i2)) { v2 = wva; i2 = j1; }
        }

        float m3 = (e == i1 || e == i2) ? -3.4e38f : z;
#pragma unroll
        for (int mm = 1; mm < 64; mm <<= 1) m3 = fmaxf(m3, __shfl_xor(m3, mm, 64));

        const float ex = expf(z - v1);
        float ssum = ex;
#pragma unroll
        for (int mm = 1; mm < 64; mm <<= 1) ssum += __shfl_xor(ssum, mm, 64);
        const float inv = 1.0f / ssum;

        float sc = fminf(fmaxf(ex * inv, EPS_), 1.0f - EPS_);
        float srz = sc / (1.0f - sc);
#pragma unroll
        for (int mm = 1; mm < 64; mm <<= 1) srz += __shfl_xor(srz, mm, 64);

        if (e == 0) {
            const float s1 = fminf(fmaxf(inv, EPS_), 1.0f - EPS_);
            const float s2v = fminf(fmaxf(expf(v2 - v1) * inv, EPS_), 1.0f - EPS_);
            ts[row * 2 + 0] = s1;
            ts[row * 2 + 1] = s2v;
            sel[row * 2 + 0] = i1;
            sel[row * 2 + 1] = i2;
            atomicAdd(&cnt[lc][i1], 1);
            atomicAdd(&cnt[lc][i2], 1);
            myrz += srz;
            if ((v1 - v2) < MARGIN || (v2 - m3) < MARGIN) {
                const int slot = atomicAdd(nflags, 1);
                flaglist[slot] = row;
            }
        }
    }

    if (lane == 0) rsum[wv] = myrz;
    __syncthreads();

    if (tid < 128) {
        const int ee = tid & 63;
        const int cc = tid >> 6;
        const int gc2 = rg * 2 + cc;
        cnt2[(size_t)ee * nchunks + gc2] = cnt[cc][ee];
        if (cnt[cc][ee]) atomicAdd(&hist[ee], cnt[cc][ee]);
    }
    if (tid == 0) {
        const int seq = sl_p[0];
        const int batch = r0 / seq;
        atomicAdd(&bsum[batch], (double)(rsum[0] + rsum[1] + rsum[2] + rsum[3]));
    }
}

// ---------------------------------------------------------------------------
// fp64 recompute of flagged near-tie rows + count-delta fixup of hist/cnt2.
// ---------------------------------------------------------------------------
__global__ __launch_bounds__(1024)
void fixup(const float* __restrict__ x, const float* __restrict__ W,
           const float* __restrict__ b, int dim, int nchunks,
           const int* __restrict__ nflags, const int* __restrict__ flaglist,
           float* __restrict__ ts, int* __restrict__ sel,
           int* __restrict__ hist, int* __restrict__ cnt2)
{
    __shared__ double red[1024];
    const int tid = threadIdx.x;
    const int e = tid & 63;
    const int q = tid >> 6;              // 0..15
    const int nf = *nflags;
    const int slice = dim >> 4;          // 128

    for (int f = blockIdx.x; f < nf; f += gridDim.x) {
        const int row = flaglist[f];
        const float* xr = x + (size_t)row * dim;
        const int k0 = q * slice;
        double a0 = 0.0, a1 = 0.0, a2 = 0.0, a3 = 0.0;
        for (int k = k0; k < k0 + slice; k += 4) {
            a0 = fma((double)xr[k + 0], (double)W[(size_t)(k + 0) * 64 + e], a0);
            a1 = fma((double)xr[k + 1], (double)W[(size_t)(k + 1) * 64 + e], a1);
            a2 = fma((double)xr[k + 2], (double)W[(size_t)(k + 2) * 64 + e], a2);
            a3 = fma((double)xr[k + 3], (double)W[(size_t)(k + 3) * 64 + e], a3);
        }
        red[tid] = (a0 + a1) + (a2 + a3);
        __syncthreads();
        for (int st = 512; st >= 64; st >>= 1) {
            if (tid < st) red[tid] += red[tid + st];
            __syncthreads();
        }
        if (tid < 64) {
            const double z = red[tid] + (double)b[e];
            double v1 = z, v2 = -1e300;
            int i1 = e, i2 = 1 << 30;
#pragma unroll
            for (int mm = 1; mm < 64; mm <<= 1) {
                const double w1 = __shfl_xor(v1, mm, 64); const int j1 = __shfl_xor(i1, mm, 64);
                const double w2 = __shfl_xor(v2, mm, 64); const int j2 = __shfl_xor(i2, mm, 64);
                if (betterd(w1, j1, v1, i1)) {
                    double nv2; int ni2;
                    if (betterd(v1, i1, w2, j2)) { nv2 = v1; ni2 = i1; }
                    else                         { nv2 = w2; ni2 = j2; }
                    v1 = w1; i1 = j1; v2 = nv2; i2 = ni2;
                } else if (betterd(w1, j1, v2, i2)) { v2 = w1; i2 = j1; }
            }
            float sl = expf((float)(z - v1));
            float ssum = sl;
#pragma unroll
            for (int mm = 1; mm < 64; mm <<= 1) ssum += __shfl_xor(ssum, mm, 64);
            const float inv = 1.0f / ssum;
            if (e == 0) {
                const float s1 = fminf(fmaxf(inv, EPS_), 1.0f - EPS_);
                const float s2 = fminf(fmaxf(expf((float)(v2 - v1)) * inv, EPS_), 1.0f - EPS_);
                const int o1 = sel[row * 2 + 0];
                const int o2 = sel[row * 2 + 1];
                ts[row * 2 + 0] = s1;
                ts[row * 2 + 1] = s2;
                if (o1 != i1 || o2 != i2) {
                    sel[row * 2 + 0] = i1;
                    sel[row * 2 + 1] = i2;
                    const int c = row >> 5;       // 32 rows per chunk
                    atomicSub(&hist[o1], 1); atomicSub(&hist[o2], 1);
                    atomicAdd(&hist[i1], 1); atomicAdd(&hist[i2], 1);
                    atomicSub(&cnt2[(size_t)o1 * nchunks + c], 1);
                    atomicSub(&cnt2[(size_t)o2 * nchunks + c], 1);
                    atomicAdd(&cnt2[(size_t)i1 * nchunks + c], 1);
                    atomicAdd(&cnt2[(size_t)i2 * nchunks + c], 1);
                }
            }
        }
        __syncthreads();
    }
}

// ---------------------------------------------------------------------------
// scan2: per-expert chunk scan + expert starts + out_cnt + rz finalize.
// ---------------------------------------------------------------------------
__global__ __launch_bounds__(1024)
void scan2(const int* __restrict__ hist, const int* __restrict__ cnt2,
           int nchunks, int* __restrict__ cbase,
           const double* __restrict__ bsum, const int* __restrict__ bs_p,
           float* __restrict__ out_cnt, float* __restrict__ out_rz)
{
    __shared__ int sc[1024];
    __shared__ int es;
    const int e = blockIdx.x;    // 64 blocks
    const int t = threadIdx.x;   // 1024

    if (t == 0) {
        int s = 0;
        for (int i = 0; i < e; ++i) s += hist[i];
        es = s;
        out_cnt[e] = (float)hist[e];
        if (e == 0) {
            const int nb = bs_p[0];
            double a = 0.0;
            for (int i = 0; i < nb; ++i) a += log(bsum[i]);
            out_rz[0] = (float)(a / nb);
        }
    }
    const int v = (t < nchunks) ? cnt2[(size_t)e * nchunks + t] : 0;
    sc[t] = v;
    __syncthreads();
#pragma unroll
    for (int off = 1; off < 1024; off <<= 1) {
        const int add = (t >= off) ? sc[t - off] : 0;
        __syncthreads();
        sc[t] += add;
        __syncthreads();
    }
    if (t < nchunks)
        cbase[(size_t)t * 64 + e] = es + sc[t] - v;   // exclusive
}

// stable scatter per 64-slot chunk
__global__ void scatter(const int* __restrict__ sel, const float* __restrict__ ts,
                        const int* __restrict__ cbase,
                        float* __restrict__ out_sc, float* __restrict__ out_idx)
{
    __shared__ int shx[64];
    const int lane = threadIdx.x;   // 64
    const int c = blockIdx.x;
    const int idx = c * 64 + lane;
    const int ex = sel[idx];
    shx[lane] = ex;
    __syncthreads();
    int pre = 0;
#pragma unroll
    for (int j = 0; j < 64; ++j) pre += (int)((j < lane) && (shx[j] == ex));
    const int pos = cbase[c * 64 + ex] + pre;
    out_sc[pos]  = ts[idx];
    out_idx[pos] = (float)(idx >> 1);
}

extern "C" void kernel_launch(void* const* d_in, const int* in_sizes, int n_in,
                              void* d_out, int out_size, void* d_ws, size_t ws_size,
                              hipStream_t stream)
{
    const float* x = (const float*)d_in[0];
    const float* W = (const float*)d_in[1];
    const float* b = (const float*)d_in[2];
    const int* bs_p = (const int*)d_in[3];
    const int* sl_p = (const int*)d_in[4];

    const int E   = in_sizes[2];           // 64
    const int dim = in_sizes[1] / E;       // 2048
    const int N   = in_sizes[0] / dim;     // 16384
    const int total = N * 2;               // slots
    const int nchunks = total / 64;        // 512 (32 rows each)

    char* ws = (char*)d_ws;
    size_t off = 0;
    int*    hist     = (int*)(ws + off); off += 256;
    double* bsum     = (double*)(ws + off); off += 512;
    int*    nflags   = (int*)(ws + off); off += 256;
    int*    done     = (int*)(ws + off); off += (size_t)(N / 64) * 4;   // 1KB
    float*  ts       = (float*)(ws + off); off += (size_t)total * 4;
    int*    sel      = (int*)(ws + off); off += (size_t)total * 4;
    int*    flaglist = (int*)(ws + off); off += (size_t)N * 4;
    int*    cnt2     = (int*)(ws + off); off += (size_t)nchunks * 64 * 4;
    int*    cbase    = (int*)(ws + off); off += (size_t)nchunks * 64 * 4;
    unsigned short* wfg = (unsigned short*)(ws + off); off += (size_t)dim * 64 * 2 * 2;
    float*  zpart    = (float*)(ws + off); off += (size_t)KSPL * N * 64 * 4;

    float* out_sc  = (float*)d_out;
    float* out_idx = out_sc + total;
    float* out_cnt = out_idx + total;
    float* out_rz  = out_cnt + E;

    hipMemsetAsync(ws, 0, 1024 + (size_t)(N / 64) * 4, stream);

    hipLaunchKernelGGL(wconv, dim3(dim * 64 / 256), dim3(256), 0, stream, W, wfg);
    hipLaunchKernelGGL(gemm_mfma, dim3((N / 64) * KSPL), dim3(256), 0, stream,
                       x, wfg, b, sl_p, dim, N, nchunks, zpart,
                       ts, sel, nflags, flaglist, hist, cnt2, bsum, done);
    hipLaunchKernelGGL(fixup, dim3(512), dim3(1024), 0, stream,
                       x, W, b, dim, nchunks, nflags, flaglist, ts, sel, hist, cnt2);
    hipLaunchKernelGGL(scan2, dim3(64), dim3(1024), 0, stream,
                       hist, cnt2, nchunks, cbase, bsum, bs_p, out_cnt, out_rz);
    hipLaunchKernelGGL(scatter, dim3(nchunks), dim3(64), 0, stream,
                       sel, ts, cbase, out_sc, out_idx);
}

// Round 23
// 91.134 us; speedup vs baseline: 2.4971x; 2.4971x over previous
//
#include <hip/hip_runtime.h>
#include <math.h>

#define EPS_ 1e-10f
#define MARGIN 4e-3f

typedef __attribute__((ext_vector_type(8))) short sh8;
typedef __attribute__((ext_vector_type(4))) float fx4;

__device__ __forceinline__ bool betterf(float v, int i, float w, int j) {
    return (v > w) || (v == w && i < j);
}
__device__ __forceinline__ bool betterd(double v, int i, double w, int j) {
    return (v > w) || (v == w && i < j);
}
__device__ __forceinline__ unsigned short f2bf(float f) {   // RNE
    unsigned u = __float_as_uint(f);
    u += 0x7fffu + ((u >> 16) & 1u);
    return (unsigned short)(u >> 16);
}
__device__ __forceinline__ float bf2f(unsigned short h) {
    return __uint_as_float(((unsigned)h) << 16);
}
__device__ __forceinline__ void cvt8(const float4 a, const float4 c, sh8& hi, sh8& lo) {
    const float v[8] = {a.x, a.y, a.z, a.w, c.x, c.y, c.z, c.w};
#pragma unroll
    for (int j = 0; j < 8; ++j) {
        const unsigned short h = f2bf(v[j]);
        hi[j] = (short)h;
        lo[j] = (short)f2bf(v[j] - bf2f(h));
    }
}
__device__ __forceinline__ void gload_lds16(const void* g, void* l) {
    __builtin_amdgcn_global_load_lds(
        (const __attribute__((address_space(1))) void*)g,
        (__attribute__((address_space(3))) void*)l, 16, 0, 0);
}

// ---------------------------------------------------------------------------
// One-time W conversion into B-fragment layout, bf16 hi/lo (layout verified).
// ---------------------------------------------------------------------------
__global__ __launch_bounds__(256)
void wconv(const float* __restrict__ W, unsigned short* __restrict__ wf)
{
    const int gid = blockIdx.x * 256 + threadIdx.x;   // dim*64
    const int e = gid & 63, k = gid >> 6;
    const int s = k >> 5, kk = k & 31, bq = kk >> 3, j = kk & 7;
    const int t = e >> 4, n = e & 15;
    const int l = n + 16 * bq;
    const float w = W[(size_t)k * 64 + e];
    const unsigned short hi = f2bf(w);
    const unsigned short lo = f2bf(w - bf2f(hi));
    const size_t base = ((size_t)s * 4 + t) * 2;
    wf[(base + 0) * 512 + l * 8 + j] = hi;
    wf[(base + 1) * 512 + l * 8 + j] = lo;
}

// ---------------------------------------------------------------------------
// MFMA GEMM, both operands LDS-staged (R18/R17 verified form: 2 buffers,
// one __syncthreads per step, 32KB LDS, 4 blocks/CU).
// ---------------------------------------------------------------------------
#define KSPL 4
__global__ __launch_bounds__(256, 4)
void gemm_mfma(const float* __restrict__ x, const unsigned short* __restrict__ wfg,
               int dim, int N, float* __restrict__ zpart)
{
    __shared__ __align__(16) char xs[2][8192];    // [buf][64 rows][32 k fp32]
    __shared__ __align__(16) char wls[2][8192];   // [buf][one K=32 W step]

    const int tid  = threadIdx.x;
    const int lane = tid & 63;
    const int wv   = tid >> 6;
    const int rgs  = N / 64;
    const int ks   = blockIdx.x / rgs;
    const int rg   = blockIdx.x % rgs;
    const int r0   = rg * 64;
    const int kslice = dim / KSPL;            // 512
    const int k0   = ks * kslice;
    const int nstep = kslice / 32;            // 16

    const int m = lane & 15;
    const int q = lane >> 4;
    const int arow = wv * 16 + m;
    const int mk = m & 7;

    const int srow_in = lane >> 3;            // 0..7
    const int sgc     = (lane & 7) ^ (srow_in & 7);

    fx4 acc[4] = {};

    const char* wbytes = (const char*)wfg;
    const size_t wstep0 = (size_t)(k0 >> 5) * 8192;

#pragma unroll
    for (int r = 0; r < 2; ++r) {
        const int row = wv * 16 + r * 8 + srow_in;
        gload_lds16(x + (size_t)(r0 + row) * dim + k0 + sgc * 4,
                    &xs[0][(wv * 16 + r * 8) * 128]);
        gload_lds16(wbytes + wstep0 + wv * 2048 + r * 1024 + lane * 16,
                    &wls[0][wv * 2048 + r * 1024]);
    }
    __syncthreads();

    for (int s = 0; s < nstep; ++s) {
        const int cb = s & 1;
        if (s + 1 < nstep) {
#pragma unroll
            for (int r = 0; r < 2; ++r) {
                const int row = wv * 16 + r * 8 + srow_in;
                gload_lds16(x + (size_t)(r0 + row) * dim + k0 + (s + 1) * 32 + sgc * 4,
                            &xs[cb ^ 1][(wv * 16 + r * 8) * 128]);
                gload_lds16(wbytes + wstep0 + (size_t)(s + 1) * 8192
                                  + wv * 2048 + r * 1024 + lane * 16,
                            &wls[cb ^ 1][wv * 2048 + r * 1024]);
            }
        }
        {
            const float4 f0 = *(const float4*)&xs[cb][arow * 128 + ((2 * q + 0) ^ mk) * 16];
            const float4 f1 = *(const float4*)&xs[cb][arow * 128 + ((2 * q + 1) ^ mk) * 16];
            sh8 ah, al;
            cvt8(f0, f1, ah, al);
#pragma unroll
            for (int te = 0; te < 4; ++te) {
                const sh8 bh = __builtin_bit_cast(sh8,
                    *(const int4*)&wls[cb][(te * 2 + 0) * 1024 + lane * 16]);
                const sh8 bl = __builtin_bit_cast(sh8,
                    *(const int4*)&wls[cb][(te * 2 + 1) * 1024 + lane * 16]);
                acc[te] = __builtin_amdgcn_mfma_f32_16x16x32_bf16(ah, bh, acc[te], 0, 0, 0);
                acc[te] = __builtin_amdgcn_mfma_f32_16x16x32_bf16(ah, bl, acc[te], 0, 0, 0);
                acc[te] = __builtin_amdgcn_mfma_f32_16x16x32_bf16(al, bh, acc[te], 0, 0, 0);
            }
        }
        __syncthreads();
    }

    const int n = lane & 15;
    const int g = lane >> 4;
    float* zp = zpart + ((size_t)ks * N + r0 + wv * 16) * 64;
#pragma unroll
    for (int te = 0; te < 4; ++te)
#pragma unroll
        for (int i = 0; i < 4; ++i)
            zp[(g * 4 + i) * 64 + te * 16 + n] = acc[te][i];
}

// ---------------------------------------------------------------------------
// Fused merge + epilogue + per-chunk histogram + per-batch rz (R18, verified).
// ---------------------------------------------------------------------------
__global__ __launch_bounds__(256)
void merge_epi32(const float* __restrict__ zpart, const float* __restrict__ b,
                 const int* __restrict__ sl_p, int N, int nchunks,
                 float* __restrict__ ts, int* __restrict__ sel,
                 int* __restrict__ nflags, int* __restrict__ flaglist,
                 int* __restrict__ hist, int* __restrict__ cnt2,
                 double* __restrict__ bsum)
{
    __shared__ int cnt[64];
    __shared__ float rsum[4];

    const int tid  = threadIdx.x;
    const int lane = tid & 63;
    const int wv   = tid >> 6;
    const int c    = blockIdx.x;          // chunk
    const int e    = lane;
    const float be = b[e];

    if (tid < 64) cnt[tid] = 0;
    __syncthreads();

    float myrz = 0.0f;

    for (int rr = 0; rr < 8; ++rr) {
        const int row = c * 32 + wv * 8 + rr;
        float z = be;
#pragma unroll
        for (int ks = 0; ks < KSPL; ++ks)
            z += zpart[((size_t)ks * N + row) * 64 + e];

        float v1 = z, v2 = -3.4e38f;
        int i1 = e, i2 = 1 << 30;
#pragma unroll
        for (int mm = 1; mm < 64; mm <<= 1) {
            const float wva = __shfl_xor(v1, mm, 64); const int j1 = __shfl_xor(i1, mm, 64);
            const float wvb = __shfl_xor(v2, mm, 64); const int j2 = __shfl_xor(i2, mm, 64);
            if (betterf(wva, j1, v1, i1)) {
                float nv2; int ni2;
                if (betterf(v1, i1, wvb, j2)) { nv2 = v1; ni2 = i1; }
                else                          { nv2 = wvb; ni2 = j2; }
                v1 = wva; i1 = j1; v2 = nv2; i2 = ni2;
            } else if (betterf(wva, j1, v2, i2)) { v2 = wva; i2 = j1; }
        }

        float m3 = (e == i1 || e == i2) ? -3.4e38f : z;
#pragma unroll
        for (int mm = 1; mm < 64; mm <<= 1) m3 = fmaxf(m3, __shfl_xor(m3, mm, 64));

        const float ex = expf(z - v1);
        float ssum = ex;
#pragma unroll
        for (int mm = 1; mm < 64; mm <<= 1) ssum += __shfl_xor(ssum, mm, 64);
        const float inv = 1.0f / ssum;

        float sc = fminf(fmaxf(ex * inv, EPS_), 1.0f - EPS_);
        float srz = sc / (1.0f - sc);
#pragma unroll
        for (int mm = 1; mm < 64; mm <<= 1) srz += __shfl_xor(srz, mm, 64);

        if (e == 0) {
            const float s1 = fminf(fmaxf(inv, EPS_), 1.0f - EPS_);
            const float s2 = fminf(fmaxf(expf(v2 - v1) * inv, EPS_), 1.0f - EPS_);
            ts[row * 2 + 0] = s1;
            ts[row * 2 + 1] = s2;
            sel[row * 2 + 0] = i1;
            sel[row * 2 + 1] = i2;
            atomicAdd(&cnt[i1], 1);
            atomicAdd(&cnt[i2], 1);
            myrz += srz;
            if ((v1 - v2) < MARGIN || (v2 - m3) < MARGIN) {
                const int slot = atomicAdd(nflags, 1);
                flaglist[slot] = row;
            }
        }
    }

    if (lane == 0) rsum[wv] = myrz;
    __syncthreads();

    if (tid < 64) {
        cnt2[(size_t)tid * nchunks + c] = cnt[tid];
        if (cnt[tid]) atomicAdd(&hist[tid], cnt[tid]);
    }
    if (tid == 0) {
        const int seq = sl_p[0];
        const int batch = (c * 32) / seq;
        atomicAdd(&bsum[batch], (double)(rsum[0] + rsum[1] + rsum[2] + rsum[3]));
    }
}

// ---------------------------------------------------------------------------
// fp64 recompute of flagged near-tie rows + count-delta fixup of hist/cnt2.
// ---------------------------------------------------------------------------
__global__ __launch_bounds__(1024)
void fixup(const float* __restrict__ x, const float* __restrict__ W,
           const float* __restrict__ b, int dim, int nchunks,
           const int* __restrict__ nflags, const int* __restrict__ flaglist,
           float* __restrict__ ts, int* __restrict__ sel,
           int* __restrict__ hist, int* __restrict__ cnt2)
{
    __shared__ double red[1024];
    const int tid = threadIdx.x;
    const int e = tid & 63;
    const int q = tid >> 6;              // 0..15
    const int nf = *nflags;
    const int slice = dim >> 4;          // 128

    for (int f = blockIdx.x; f < nf; f += gridDim.x) {
        const int row = flaglist[f];
        const float* xr = x + (size_t)row * dim;
        const int k0 = q * slice;
        double a0 = 0.0, a1 = 0.0, a2 = 0.0, a3 = 0.0;
        for (int k = k0; k < k0 + slice; k += 4) {
            a0 = fma((double)xr[k + 0], (double)W[(size_t)(k + 0) * 64 + e], a0);
            a1 = fma((double)xr[k + 1], (double)W[(size_t)(k + 1) * 64 + e], a1);
            a2 = fma((double)xr[k + 2], (double)W[(size_t)(k + 2) * 64 + e], a2);
            a3 = fma((double)xr[k + 3], (double)W[(size_t)(k + 3) * 64 + e], a3);
        }
        red[tid] = (a0 + a1) + (a2 + a3);
        __syncthreads();
        for (int st = 512; st >= 64; st >>= 1) {
            if (tid < st) red[tid] += red[tid + st];
            __syncthreads();
        }
        if (tid < 64) {
            const double z = red[tid] + (double)b[e];
            double v1 = z, v2 = -1e300;
            int i1 = e, i2 = 1 << 30;
#pragma unroll
            for (int mm = 1; mm < 64; mm <<= 1) {
                const double w1 = __shfl_xor(v1, mm, 64); const int j1 = __shfl_xor(i1, mm, 64);
                const double w2 = __shfl_xor(v2, mm, 64); const int j2 = __shfl_xor(i2, mm, 64);
                if (betterd(w1, j1, v1, i1)) {
                    double nv2; int ni2;
                    if (betterd(v1, i1, w2, j2)) { nv2 = v1; ni2 = i1; }
                    else                         { nv2 = w2; ni2 = j2; }
                    v1 = w1; i1 = j1; v2 = nv2; i2 = ni2;
                } else if (betterd(w1, j1, v2, i2)) { v2 = w1; i2 = j1; }
            }
            float sl = expf((float)(z - v1));
            float ssum = sl;
#pragma unroll
            for (int mm = 1; mm < 64; mm <<= 1) ssum += __shfl_xor(ssum, mm, 64);
            const float inv = 1.0f / ssum;
            if (e == 0) {
                const float s1 = fminf(fmaxf(inv, EPS_), 1.0f - EPS_);
                const float s2 = fminf(fmaxf(expf((float)(v2 - v1)) * inv, EPS_), 1.0f - EPS_);
                const int o1 = sel[row * 2 + 0];
                const int o2 = sel[row * 2 + 1];
                ts[row * 2 + 0] = s1;
                ts[row * 2 + 1] = s2;
                if (o1 != i1 || o2 != i2) {
                    sel[row * 2 + 0] = i1;
                    sel[row * 2 + 1] = i2;
                    const int c = row >> 5;       // 32 rows per chunk
                    atomicSub(&hist[o1], 1); atomicSub(&hist[o2], 1);
                    atomicAdd(&hist[i1], 1); atomicAdd(&hist[i2], 1);
                    atomicSub(&cnt2[(size_t)o1 * nchunks + c], 1);
                    atomicSub(&cnt2[(size_t)o2 * nchunks + c], 1);
                    atomicAdd(&cnt2[(size_t)i1 * nchunks + c], 1);
                    atomicAdd(&cnt2[(size_t)i2 * nchunks + c], 1);
                }
            }
        }
        __syncthreads();
    }
}

// ---------------------------------------------------------------------------
// scan2: per-expert chunk scan + expert starts + out_cnt + rz finalize.
// ---------------------------------------------------------------------------
__global__ __launch_bounds__(1024)
void scan2(const int* __restrict__ hist, const int* __restrict__ cnt2,
           int nchunks, int* __restrict__ cbase,
           const double* __restrict__ bsum, const int* __restrict__ bs_p,
           float* __restrict__ out_cnt, float* __restrict__ out_rz)
{
    __shared__ int sc[1024];
    __shared__ int es;
    const int e = blockIdx.x;    // 64 blocks
    const int t = threadIdx.x;   // 1024

    if (t == 0) {
        int s = 0;
        for (int i = 0; i < e; ++i) s += hist[i];
        es = s;
        out_cnt[e] = (float)hist[e];
        if (e == 0) {
            const int nb = bs_p[0];
            double a = 0.0;
            for (int i = 0; i < nb; ++i) a += log(bsum[i]);
            out_rz[0] = (float)(a / nb);
        }
    }
    const int v = (t < nchunks) ? cnt2[(size_t)e * nchunks + t] : 0;
    sc[t] = v;
    __syncthreads();
#pragma unroll
    for (int off = 1; off < 1024; off <<= 1) {
        const int add = (t >= off) ? sc[t - off] : 0;
        __syncthreads();
        sc[t] += add;
        __syncthreads();
    }
    if (t < nchunks)
        cbase[(size_t)t * 64 + e] = es + sc[t] - v;   // exclusive
}

// stable scatter per 64-slot chunk
__global__ void scatter(const int* __restrict__ sel, const float* __restrict__ ts,
                        const int* __restrict__ cbase,
                        float* __restrict__ out_sc, float* __restrict__ out_idx)
{
    __shared__ int shx[64];
    const int lane = threadIdx.x;   // 64
    const int c = blockIdx.x;
    const int idx = c * 64 + lane;
    const int ex = sel[idx];
    shx[lane] = ex;
    __syncthreads();
    int pre = 0;
#pragma unroll
    for (int j = 0; j < 64; ++j) pre += (int)((j < lane) && (shx[j] == ex));
    const int pos = cbase[c * 64 + ex] + pre;
    out_sc[pos]  = ts[idx];
    out_idx[pos] = (float)(idx >> 1);
}

extern "C" void kernel_launch(void* const* d_in, const int* in_sizes, int n_in,
                              void* d_out, int out_size, void* d_ws, size_t ws_size,
                              hipStream_t stream)
{
    const float* x = (const float*)d_in[0];
    const float* W = (const float*)d_in[1];
    const float* b = (const float*)d_in[2];
    const int* bs_p = (const int*)d_in[3];
    const int* sl_p = (const int*)d_in[4];

    const int E   = in_sizes[2];           // 64
    const int dim = in_sizes[1] / E;       // 2048
    const int N   = in_sizes[0] / dim;     // 16384
    const int total = N * 2;               // slots
    const int nchunks = total / 64;        // 512

    char* ws = (char*)d_ws;
    size_t off = 0;
    int*    hist     = (int*)(ws + off); off += 256;
    double* bsum     = (double*)(ws + off); off += 512;
    int*    nflags   = (int*)(ws + off); off += 256;
    float*  ts       = (float*)(ws + off); off += (size_t)total * 4;
    int*    sel      = (int*)(ws + off); off += (size_t)total * 4;
    int*    flaglist = (int*)(ws + off); off += (size_t)N * 4;
    int*    cnt2     = (int*)(ws + off); off += (size_t)nchunks * 64 * 4;
    int*    cbase    = (int*)(ws + off); off += (size_t)nchunks * 64 * 4;
    unsigned short* wfg = (unsigned short*)(ws + off); off += (size_t)dim * 64 * 2 * 2;
    float*  zpart    = (float*)(ws + off); off += (size_t)KSPL * N * 64 * 4;

    float* out_sc  = (float*)d_out;
    float* out_idx = out_sc + total;
    float* out_cnt = out_idx + total;
    float* out_rz  = out_cnt + E;

    hipMemsetAsync(ws, 0, 1024, stream);

    hipLaunchKernelGGL(wconv, dim3(dim * 64 / 256), dim3(256), 0, stream, W, wfg);
    hipLaunchKernelGGL(gemm_mfma, dim3((N / 64) * KSPL), dim3(256), 0, stream,
                       x, wfg, dim, N, zpart);
    hipLaunchKernelGGL(merge_epi32, dim3(nchunks), dim3(256), 0, stream,
                       zpart, b, sl_p, N, nchunks, ts, sel, nflags, flaglist,
                       hist, cnt2, bsum);
    hipLaunchKernelGGL(fixup, dim3(512), dim3(1024), 0, stream,
                       x, W, b, dim, nchunks, nflags, flaglist, ts, sel, hist, cnt2);
    hipLaunchKernelGGL(scan2, dim3(64), dim3(1024), 0, stream,
                       hist, cnt2, nchunks, cbase, bsum, bs_p, out_cnt, out_rz);
    hipLaunchKernelGGL(scatter, dim3(nchunks), dim3(64), 0, stream,
                       sel, ts, cbase, out_sc, out_idx);
}

// Round 24
// 90.124 us; speedup vs baseline: 2.5251x; 1.0112x over previous
//
#include <hip/hip_runtime.h>
#include <math.h>

#define EPS_ 1e-10f
#define MARGIN 4e-3f

typedef __attribute__((ext_vector_type(8))) short sh8;
typedef __attribute__((ext_vector_type(4))) float fx4;

__device__ __forceinline__ bool betterf(float v, int i, float w, int j) {
    return (v > w) || (v == w && i < j);
}
__device__ __forceinline__ bool betterd(double v, int i, double w, int j) {
    return (v > w) || (v == w && i < j);
}
__device__ __forceinline__ unsigned short f2bf(float f) {   // RNE
    unsigned u = __float_as_uint(f);
    u += 0x7fffu + ((u >> 16) & 1u);
    return (unsigned short)(u >> 16);
}
__device__ __forceinline__ float bf2f(unsigned short h) {
    return __uint_as_float(((unsigned)h) << 16);
}
__device__ __forceinline__ void cvt8(const float4 a, const float4 c, sh8& hi, sh8& lo) {
    const float v[8] = {a.x, a.y, a.z, a.w, c.x, c.y, c.z, c.w};
#pragma unroll
    for (int j = 0; j < 8; ++j) {
        const unsigned short h = f2bf(v[j]);
        hi[j] = (short)h;
        lo[j] = (short)f2bf(v[j] - bf2f(h));
    }
}
__device__ __forceinline__ void gload_lds16(const void* g, void* l) {
    __builtin_amdgcn_global_load_lds(
        (const __attribute__((address_space(1))) void*)g,
        (__attribute__((address_space(3))) void*)l, 16, 0, 0);
}

// ---------------------------------------------------------------------------
// One-time W conversion into B-fragment layout, bf16 hi/lo (layout verified).
// ---------------------------------------------------------------------------
__global__ __launch_bounds__(256)
void wconv(const float* __restrict__ W, unsigned short* __restrict__ wf)
{
    const int gid = blockIdx.x * 256 + threadIdx.x;   // dim*64
    const int e = gid & 63, k = gid >> 6;
    const int s = k >> 5, kk = k & 31, bq = kk >> 3, j = kk & 7;
    const int t = e >> 4, n = e & 15;
    const int l = n + 16 * bq;
    const float w = W[(size_t)k * 64 + e];
    const unsigned short hi = f2bf(w);
    const unsigned short lo = f2bf(w - bf2f(hi));
    const size_t base = ((size_t)s * 4 + t) * 2;
    wf[(base + 0) * 512 + l * 8 + j] = hi;
    wf[(base + 1) * 512 + l * 8 + j] = lo;
}

// ---------------------------------------------------------------------------
// MFMA GEMM, both operands LDS-staged (R18 verified form: 2 buffers, one
// __syncthreads per step, 32KB LDS, 4 blocks/CU) + T1 XCD-aware grid
// swizzle: swz = (bid&7)*(nwg/8) + bid>>3 (bijective, nwg%8==0) clusters
// same-ks blocks (sharing one 128KB wfg slice) onto one XCD -> per-XCD W
// L2 footprint 512KB -> 128KB, contiguous x row range per XCD.
// ---------------------------------------------------------------------------
#define KSPL 4
__global__ __launch_bounds__(256, 4)
void gemm_mfma(const float* __restrict__ x, const unsigned short* __restrict__ wfg,
               int dim, int N, float* __restrict__ zpart)
{
    __shared__ __align__(16) char xs[2][8192];    // [buf][64 rows][32 k fp32]
    __shared__ __align__(16) char wls[2][8192];   // [buf][one K=32 W step]

    const int tid  = threadIdx.x;
    const int lane = tid & 63;
    const int wv   = tid >> 6;
    const int rgs  = N / 64;
    // XCD-aware swizzle (bijective since gridDim.x = rgs*KSPL is a multiple of 8)
    const int cpx  = (rgs * KSPL) >> 3;
    const int swz  = (blockIdx.x & 7) * cpx + (blockIdx.x >> 3);
    const int ks   = swz / rgs;
    const int rg   = swz % rgs;
    const int r0   = rg * 64;
    const int kslice = dim / KSPL;            // 512
    const int k0   = ks * kslice;
    const int nstep = kslice / 32;            // 16

    const int m = lane & 15;
    const int q = lane >> 4;
    const int arow = wv * 16 + m;
    const int mk = m & 7;

    const int srow_in = lane >> 3;            // 0..7
    const int sgc     = (lane & 7) ^ (srow_in & 7);

    fx4 acc[4] = {};

    const char* wbytes = (const char*)wfg;
    const size_t wstep0 = (size_t)(k0 >> 5) * 8192;

#pragma unroll
    for (int r = 0; r < 2; ++r) {
        const int row = wv * 16 + r * 8 + srow_in;
        gload_lds16(x + (size_t)(r0 + row) * dim + k0 + sgc * 4,
                    &xs[0][(wv * 16 + r * 8) * 128]);
        gload_lds16(wbytes + wstep0 + wv * 2048 + r * 1024 + lane * 16,
                    &wls[0][wv * 2048 + r * 1024]);
    }
    __syncthreads();

    for (int s = 0; s < nstep; ++s) {
        const int cb = s & 1;
        if (s + 1 < nstep) {
#pragma unroll
            for (int r = 0; r < 2; ++r) {
                const int row = wv * 16 + r * 8 + srow_in;
                gload_lds16(x + (size_t)(r0 + row) * dim + k0 + (s + 1) * 32 + sgc * 4,
                            &xs[cb ^ 1][(wv * 16 + r * 8) * 128]);
                gload_lds16(wbytes + wstep0 + (size_t)(s + 1) * 8192
                                  + wv * 2048 + r * 1024 + lane * 16,
                            &wls[cb ^ 1][wv * 2048 + r * 1024]);
            }
        }
        {
            const float4 f0 = *(const float4*)&xs[cb][arow * 128 + ((2 * q + 0) ^ mk) * 16];
            const float4 f1 = *(const float4*)&xs[cb][arow * 128 + ((2 * q + 1) ^ mk) * 16];
            sh8 ah, al;
            cvt8(f0, f1, ah, al);
#pragma unroll
            for (int te = 0; te < 4; ++te) {
                const sh8 bh = __builtin_bit_cast(sh8,
                    *(const int4*)&wls[cb][(te * 2 + 0) * 1024 + lane * 16]);
                const sh8 bl = __builtin_bit_cast(sh8,
                    *(const int4*)&wls[cb][(te * 2 + 1) * 1024 + lane * 16]);
                acc[te] = __builtin_amdgcn_mfma_f32_16x16x32_bf16(ah, bh, acc[te], 0, 0, 0);
                acc[te] = __builtin_amdgcn_mfma_f32_16x16x32_bf16(ah, bl, acc[te], 0, 0, 0);
                acc[te] = __builtin_amdgcn_mfma_f32_16x16x32_bf16(al, bh, acc[te], 0, 0, 0);
            }
        }
        __syncthreads();
    }

    const int n = lane & 15;
    const int g = lane >> 4;
    float* zp = zpart + ((size_t)ks * N + r0 + wv * 16) * 64;
#pragma unroll
    for (int te = 0; te < 4; ++te)
#pragma unroll
        for (int i = 0; i < 4; ++i)
            zp[(g * 4 + i) * 64 + te * 16 + n] = acc[te][i];
}

// ---------------------------------------------------------------------------
// Fused merge + epilogue + per-chunk histogram + per-batch rz (R18, verified).
// ---------------------------------------------------------------------------
__global__ __launch_bounds__(256)
void merge_epi32(const float* __restrict__ zpart, const float* __restrict__ b,
                 const int* __restrict__ sl_p, int N, int nchunks,
                 float* __restrict__ ts, int* __restrict__ sel,
                 int* __restrict__ nflags, int* __restrict__ flaglist,
                 int* __restrict__ hist, int* __restrict__ cnt2,
                 double* __restrict__ bsum)
{
    __shared__ int cnt[64];
    __shared__ float rsum[4];

    const int tid  = threadIdx.x;
    const int lane = tid & 63;
    const int wv   = tid >> 6;
    const int c    = blockIdx.x;          // chunk
    const int e    = lane;
    const float be = b[e];

    if (tid < 64) cnt[tid] = 0;
    __syncthreads();

    float myrz = 0.0f;

    for (int rr = 0; rr < 8; ++rr) {
        const int row = c * 32 + wv * 8 + rr;
        float z = be;
#pragma unroll
        for (int ks = 0; ks < KSPL; ++ks)
            z += zpart[((size_t)ks * N + row) * 64 + e];

        float v1 = z, v2 = -3.4e38f;
        int i1 = e, i2 = 1 << 30;
#pragma unroll
        for (int mm = 1; mm < 64; mm <<= 1) {
            const float wva = __shfl_xor(v1, mm, 64); const int j1 = __shfl_xor(i1, mm, 64);
            const float wvb = __shfl_xor(v2, mm, 64); const int j2 = __shfl_xor(i2, mm, 64);
            if (betterf(wva, j1, v1, i1)) {
                float nv2; int ni2;
                if (betterf(v1, i1, wvb, j2)) { nv2 = v1; ni2 = i1; }
                else                          { nv2 = wvb; ni2 = j2; }
                v1 = wva; i1 = j1; v2 = nv2; i2 = ni2;
            } else if (betterf(wva, j1, v2, i2)) { v2 = wva; i2 = j1; }
        }

        float m3 = (e == i1 || e == i2) ? -3.4e38f : z;
#pragma unroll
        for (int mm = 1; mm < 64; mm <<= 1) m3 = fmaxf(m3, __shfl_xor(m3, mm, 64));

        const float ex = expf(z - v1);
        float ssum = ex;
#pragma unroll
        for (int mm = 1; mm < 64; mm <<= 1) ssum += __shfl_xor(ssum, mm, 64);
        const float inv = 1.0f / ssum;

        float sc = fminf(fmaxf(ex * inv, EPS_), 1.0f - EPS_);
        float srz = sc / (1.0f - sc);
#pragma unroll
        for (int mm = 1; mm < 64; mm <<= 1) srz += __shfl_xor(srz, mm, 64);

        if (e == 0) {
            const float s1 = fminf(fmaxf(inv, EPS_), 1.0f - EPS_);
            const float s2 = fminf(fmaxf(expf(v2 - v1) * inv, EPS_), 1.0f - EPS_);
            ts[row * 2 + 0] = s1;
            ts[row * 2 + 1] = s2;
            sel[row * 2 + 0] = i1;
            sel[row * 2 + 1] = i2;
            atomicAdd(&cnt[i1], 1);
            atomicAdd(&cnt[i2], 1);
            myrz += srz;
            if ((v1 - v2) < MARGIN || (v2 - m3) < MARGIN) {
                const int slot = atomicAdd(nflags, 1);
                flaglist[slot] = row;
            }
        }
    }

    if (lane == 0) rsum[wv] = myrz;
    __syncthreads();

    if (tid < 64) {
        cnt2[(size_t)tid * nchunks + c] = cnt[tid];
        if (cnt[tid]) atomicAdd(&hist[tid], cnt[tid]);
    }
    if (tid == 0) {
        const int seq = sl_p[0];
        const int batch = (c * 32) / seq;
        atomicAdd(&bsum[batch], (double)(rsum[0] + rsum[1] + rsum[2] + rsum[3]));
    }
}

// ---------------------------------------------------------------------------
// fp64 recompute of flagged near-tie rows + count-delta fixup of hist/cnt2.
// ---------------------------------------------------------------------------
__global__ __launch_bounds__(1024)
void fixup(const float* __restrict__ x, const float* __restrict__ W,
           const float* __restrict__ b, int dim, int nchunks,
           const int* __restrict__ nflags, const int* __restrict__ flaglist,
           float* __restrict__ ts, int* __restrict__ sel,
           int* __restrict__ hist, int* __restrict__ cnt2)
{
    __shared__ double red[1024];
    const int tid = threadIdx.x;
    const int e = tid & 63;
    const int q = tid >> 6;              // 0..15
    const int nf = *nflags;
    const int slice = dim >> 4;          // 128

    for (int f = blockIdx.x; f < nf; f += gridDim.x) {
        const int row = flaglist[f];
        const float* xr = x + (size_t)row * dim;
        const int k0 = q * slice;
        double a0 = 0.0, a1 = 0.0, a2 = 0.0, a3 = 0.0;
        for (int k = k0; k < k0 + slice; k += 4) {
            a0 = fma((double)xr[k + 0], (double)W[(size_t)(k + 0) * 64 + e], a0);
            a1 = fma((double)xr[k + 1], (double)W[(size_t)(k + 1) * 64 + e], a1);
            a2 = fma((double)xr[k + 2], (double)W[(size_t)(k + 2) * 64 + e], a2);
            a3 = fma((double)xr[k + 3], (double)W[(size_t)(k + 3) * 64 + e], a3);
        }
        red[tid] = (a0 + a1) + (a2 + a3);
        __syncthreads();
        for (int st = 512; st >= 64; st >>= 1) {
            if (tid < st) red[tid] += red[tid + st];
            __syncthreads();
        }
        if (tid < 64) {
            const double z = red[tid] + (double)b[e];
            double v1 = z, v2 = -1e300;
            int i1 = e, i2 = 1 << 30;
#pragma unroll
            for (int mm = 1; mm < 64; mm <<= 1) {
                const double w1 = __shfl_xor(v1, mm, 64); const int j1 = __shfl_xor(i1, mm, 64);
                const double w2 = __shfl_xor(v2, mm, 64); const int j2 = __shfl_xor(i2, mm, 64);
                if (betterd(w1, j1, v1, i1)) {
                    double nv2; int ni2;
                    if (betterd(v1, i1, w2, j2)) { nv2 = v1; ni2 = i1; }
                    else                         { nv2 = w2; ni2 = j2; }
                    v1 = w1; i1 = j1; v2 = nv2; i2 = ni2;
                } else if (betterd(w1, j1, v2, i2)) { v2 = w1; i2 = j1; }
            }
            float sl = expf((float)(z - v1));
            float ssum = sl;
#pragma unroll
            for (int mm = 1; mm < 64; mm <<= 1) ssum += __shfl_xor(ssum, mm, 64);
            const float inv = 1.0f / ssum;
            if (e == 0) {
                const float s1 = fminf(fmaxf(inv, EPS_), 1.0f - EPS_);
                const float s2 = fminf(fmaxf(expf((float)(v2 - v1)) * inv, EPS_), 1.0f - EPS_);
                const int o1 = sel[row * 2 + 0];
                const int o2 = sel[row * 2 + 1];
                ts[row * 2 + 0] = s1;
                ts[row * 2 + 1] = s2;
                if (o1 != i1 || o2 != i2) {
                    sel[row * 2 + 0] = i1;
                    sel[row * 2 + 1] = i2;
                    const int c = row >> 5;       // 32 rows per chunk
                    atomicSub(&hist[o1], 1); atomicSub(&hist[o2], 1);
                    atomicAdd(&hist[i1], 1); atomicAdd(&hist[i2], 1);
                    atomicSub(&cnt2[(size_t)o1 * nchunks + c], 1);
                    atomicSub(&cnt2[(size_t)o2 * nchunks + c], 1);
                    atomicAdd(&cnt2[(size_t)i1 * nchunks + c], 1);
                    atomicAdd(&cnt2[(size_t)i2 * nchunks + c], 1);
                }
            }
        }
        __syncthreads();
    }
}

// ---------------------------------------------------------------------------
// scan2: per-expert chunk scan + expert starts + out_cnt + rz finalize.
// ---------------------------------------------------------------------------
__global__ __launch_bounds__(1024)
void scan2(const int* __restrict__ hist, const int* __restrict__ cnt2,
           int nchunks, int* __restrict__ cbase,
           const double* __restrict__ bsum, const int* __restrict__ bs_p,
           float* __restrict__ out_cnt, float* __restrict__ out_rz)
{
    __shared__ int sc[1024];
    __shared__ int es;
    const int e = blockIdx.x;    // 64 blocks
    const int t = threadIdx.x;   // 1024

    if (t == 0) {
        int s = 0;
        for (int i = 0; i < e; ++i) s += hist[i];
        es = s;
        out_cnt[e] = (float)hist[e];
        if (e == 0) {
            const int nb = bs_p[0];
            double a = 0.0;
            for (int i = 0; i < nb; ++i) a += log(bsum[i]);
            out_rz[0] = (float)(a / nb);
        }
    }
    const int v = (t < nchunks) ? cnt2[(size_t)e * nchunks + t] : 0;
    sc[t] = v;
    __syncthreads();
#pragma unroll
    for (int off = 1; off < 1024; off <<= 1) {
        const int add = (t >= off) ? sc[t - off] : 0;
        __syncthreads();
        sc[t] += add;
        __syncthreads();
    }
    if (t < nchunks)
        cbase[(size_t)t * 64 + e] = es + sc[t] - v;   // exclusive
}

// stable scatter per 64-slot chunk
__global__ void scatter(const int* __restrict__ sel, const float* __restrict__ ts,
                        const int* __restrict__ cbase,
                        float* __restrict__ out_sc, float* __restrict__ out_idx)
{
    __shared__ int shx[64];
    const int lane = threadIdx.x;   // 64
    const int c = blockIdx.x;
    const int idx = c * 64 + lane;
    const int ex = sel[idx];
    shx[lane] = ex;
    __syncthreads();
    int pre = 0;
#pragma unroll
    for (int j = 0; j < 64; ++j) pre += (int)((j < lane) && (shx[j] == ex));
    const int pos = cbase[c * 64 + ex] + pre;
    out_sc[pos]  = ts[idx];
    out_idx[pos] = (float)(idx >> 1);
}

extern "C" void kernel_launch(void* const* d_in, const int* in_sizes, int n_in,
                              void* d_out, int out_size, void* d_ws, size_t ws_size,
                              hipStream_t stream)
{
    const float* x = (const float*)d_in[0];
    const float* W = (const float*)d_in[1];
    const float* b = (const float*)d_in[2];
    const int* bs_p = (const int*)d_in[3];
    const int* sl_p = (const int*)d_in[4];

    const int E   = in_sizes[2];           // 64
    const int dim = in_sizes[1] / E;       // 2048
    const int N   = in_sizes[0] / dim;     // 16384
    const int total = N * 2;               // slots
    const int nchunks = total / 64;        // 512

    char* ws = (char*)d_ws;
    size_t off = 0;
    int*    hist     = (int*)(ws + off); off += 256;
    double* bsum     = (double*)(ws + off); off += 512;
    int*    nflags   = (int*)(ws + off); off += 256;
    float*  ts       = (float*)(ws + off); off += (size_t)total * 4;
    int*    sel      = (int*)(ws + off); off += (size_t)total * 4;
    int*    flaglist = (int*)(ws + off); off += (size_t)N * 4;
    int*    cnt2     = (int*)(ws + off); off += (size_t)nchunks * 64 * 4;
    int*    cbase    = (int*)(ws + off); off += (size_t)nchunks * 64 * 4;
    unsigned short* wfg = (unsigned short*)(ws + off); off += (size_t)dim * 64 * 2 * 2;
    float*  zpart    = (float*)(ws + off); off += (size_t)KSPL * N * 64 * 4;

    float* out_sc  = (float*)d_out;
    float* out_idx = out_sc + total;
    float* out_cnt = out_idx + total;
    float* out_rz  = out_cnt + E;

    hipMemsetAsync(ws, 0, 1024, stream);

    hipLaunchKernelGGL(wconv, dim3(dim * 64 / 256), dim3(256), 0, stream, W, wfg);
    hipLaunchKernelGGL(gemm_mfma, dim3((N / 64) * KSPL), dim3(256), 0, stream,
                       x, wfg, dim, N, zpart);
    hipLaunchKernelGGL(merge_epi32, dim3(nchunks), dim3(256), 0, stream,
                       zpart, b, sl_p, N, nchunks, ts, sel, nflags, flaglist,
                       hist, cnt2, bsum);
    hipLaunchKernelGGL(fixup, dim3(512), dim3(1024), 0, stream,
                       x, W, b, dim, nchunks, nflags, flaglist, ts, sel, hist, cnt2);
    hipLaunchKernelGGL(scan2, dim3(64), dim3(1024), 0, stream,
                       hist, cnt2, nchunks, cbase, bsum, bs_p, out_cnt, out_rz);
    hipLaunchKernelGGL(scatter, dim3(nchunks), dim3(64), 0, stream,
                       sel, ts, cbase, out_sc, out_idx);
}